// Round 1
// baseline (223.569 us; speedup 1.0000x reference)
//
#include <hip/hip_runtime.h>
#include <math.h>

// RotaryEmbedding: x (4,16,8192,64) fp32. Rotate first ROTATE=4 pairs
// (elements 0..7) of last dim; copy elements 8..63 through.
// direction = sigmoid(dparam[0])*2-1 = tanh(dparam[0]/2)
// theta_k = direction * thetas[k];  (xi,xj) -> (xi*c+xj*s, -xi*s+xj*c)
//
// Memory-bound: 128 MiB read + 128 MiB write. One thread per float4
// (16B/lane, coalesced). Row = 16 float4s; only pos 0 and 1 rotate.

#define DIM 64
#define F4_PER_ROW (DIM / 4)   // 16

__global__ __launch_bounds__(256) void rope_kernel(
    const float4* __restrict__ x,
    const float* __restrict__ dparam,
    const float* __restrict__ thetas,
    float4* __restrict__ out,
    int n4)
{
    int idx = blockIdx.x * blockDim.x + threadIdx.x;
    if (idx >= n4) return;

    float4 v = x[idx];
    int pos = idx & (F4_PER_ROW - 1);   // position within the 64-float row

    if (pos < 2) {
        // pairs handled by this float4: pair0 = pos*2, pair0+1
        float direction = tanhf(dparam[0] * 0.5f);  // sigmoid(d)*2-1
        int p0 = pos * 2;
        float t0 = direction * thetas[p0];
        float t1 = direction * thetas[p0 + 1];
        float c0 = cosf(t0), s0 = sinf(t0);
        float c1 = cosf(t1), s1 = sinf(t1);
        float xi0 = v.x, xj0 = v.y;
        float xi1 = v.z, xj1 = v.w;
        v.x =  xi0 * c0 + xj0 * s0;
        v.y = -xi0 * s0 + xj0 * c0;
        v.z =  xi1 * c1 + xj1 * s1;
        v.w = -xi1 * s1 + xj1 * c1;
    }

    out[idx] = v;
}

extern "C" void kernel_launch(void* const* d_in, const int* in_sizes, int n_in,
                              void* d_out, int out_size, void* d_ws, size_t ws_size,
                              hipStream_t stream)
{
    const float* x      = (const float*)d_in[0];
    const float* dparam = (const float*)d_in[1];
    const float* thetas = (const float*)d_in[2];
    float* out          = (float*)d_out;

    int n  = in_sizes[0];        // 33,554,432
    int n4 = n / 4;              // 8,388,608 float4s

    const int block = 256;
    int grid = (n4 + block - 1) / block;

    rope_kernel<<<grid, block, 0, stream>>>(
        (const float4*)x, dparam, thetas, (float4*)out, n4);
}